// Round 2
// baseline (298.716 us; speedup 1.0000x reference)
//
#include <hip/hip_runtime.h>
#include <hip/hip_bf16.h>

// Problem constants: B=4, S=2048, DK=DV=1024, H=16, DKH=DVH=64.
// Harness dtypes: ALL inputs f32, output f32 (npz-size evidence).
// Internal compute: bf16 MFMA with f32 accumulation (threshold = 2% of max|ref|).

typedef __attribute__((ext_vector_type(8))) __bf16 bfv8;   // MFMA A/B frag (4 VGPR)
typedef __attribute__((ext_vector_type(4))) float f32x4;   // MFMA C/D frag
typedef __attribute__((ext_vector_type(4))) short short4v; // 8B packed store
typedef unsigned int u32;

__device__ __forceinline__ f32x4 mfma16(bfv8 a, bfv8 b, f32x4 c) {
  return __builtin_amdgcn_mfma_f32_16x16x32_bf16(a, b, c, 0, 0, 0);
}

__device__ __forceinline__ void gload16(const void* g, void* l) {
  // async global->LDS, 16B per lane; LDS dest is wave-uniform base (+lane*16 in HW)
  __builtin_amdgcn_global_load_lds(
      (const __attribute__((address_space(1))) u32*)g,
      (__attribute__((address_space(3))) u32*)l, 16, 0, 0);
}

__device__ __forceinline__ short f2bf(float f) {  // round-to-nearest-even
  u32 u; __builtin_memcpy(&u, &f, 4);
  u += 0x7fffu + ((u >> 16) & 1u);
  return (short)(u >> 16);
}

// ---------------------------------------------------------------------------
// Kernel A: convert Q/K/V activations f32 -> bf16 into ws ([3][8192][1024]).
__global__ __launch_bounds__(256) void cvt_to_bf16(
    const float* __restrict__ Q, const float* __restrict__ K,
    const float* __restrict__ V, short* __restrict__ dst) {
  const size_t N = (size_t)8388608;  // 8192*1024
  size_t idx = (size_t)blockIdx.x * 256 + threadIdx.x;
  for (size_t c = idx; c < 3 * N / 4; c += (size_t)gridDim.x * 256) {
    size_t i = c * 4;
    const float* src = i < N ? Q + i : (i < 2 * N ? K + i - N : V + i - 2 * N);
    float4 v = *(const float4*)src;
    short4v o;
    o[0] = f2bf(v.x); o[1] = f2bf(v.y); o[2] = f2bf(v.z); o[3] = f2bf(v.w);
    *(short4v*)(dst + i) = o;
  }
}

// ---------------------------------------------------------------------------
// Kernel B: transpose+convert weights into bf16 WT[mode][N=1024][K=1024].
//   mode 0..3 = WqT,WkT,WvT,WoT. Wq/Wk/Wv are [H][K][64]: WT[n][d]=W[n>>6][d][n&63].
//   Wo is [K][N]: WoT[n][k]=Wo[k][n].
__global__ __launch_bounds__(256) void transpose_w(
    const float* __restrict__ Wq, const float* __restrict__ Wk,
    const float* __restrict__ Wv, const float* __restrict__ Wo,
    short* __restrict__ WT) {
  int widx = blockIdx.y;
  int idx = blockIdx.x * 256 + threadIdx.x;   // 1M elements per matrix
  int n = idx >> 10, d = idx & 1023;
  const float* src = widx == 0 ? Wq : widx == 1 ? Wk : widx == 2 ? Wv : Wo;
  float v;
  if (widx < 3) v = src[((size_t)(n >> 6) * 1024 + d) * 64 + (n & 63)];
  else          v = src[(size_t)d * 1024 + n];
  WT[(size_t)widx * 1048576 + idx] = f2bf(v);
}

// ---------------------------------------------------------------------------
// Kernel C: 128x128-tile GEMM  C = A[M x 1024] * WT[mode]^T + bias, K=1024.
// mode 0: q proj  -> q_ws[b,h,s,e]  scaled by 0.125 (fold 1/sqrt(64) into q)
// mode 1: k proj  -> k_ws[b,h,s,e]
// mode 2: v proj  -> vT_ws[b,h,e,s] (transposed for PV B-operand)
// mode 3: out proj-> d_out[m][n] (f32)
// LDS tiles [128 rows][64 k] bf16, XOR-swizzled: byte ^= ((row&7)<<4).
// global_load_lds writes linearly -> swizzle applied on SOURCE address
// and on the ds_read address (both-sides rule, involution).
__global__ __launch_bounds__(256) void gemm128(
    const short* __restrict__ A0, const short* __restrict__ A1,
    const short* __restrict__ A2, const short* __restrict__ A3,
    const short* __restrict__ WT,
    const float* __restrict__ b0, const float* __restrict__ b1,
    const float* __restrict__ b2, const float* __restrict__ b3,
    short* __restrict__ o0, short* __restrict__ o1,
    short* __restrict__ o2, float* __restrict__ o3,
    int mode_base) {
  const int mode = mode_base + blockIdx.z;
  const short* A    = mode == 0 ? A0 : mode == 1 ? A1 : mode == 2 ? A2 : A3;
  const float* bias = mode == 0 ? b0 : mode == 1 ? b1 : mode == 2 ? b2 : b3;
  const short* BT   = WT + (size_t)mode * 1048576;

  const int m0 = blockIdx.y * 128, n0 = blockIdx.x * 128;
  const int tid = threadIdx.x, w = tid >> 6, l = tid & 63;
  const int g = l >> 4, q4 = l & 15;
  const int wm = w >> 1, wn = w & 1;   // 2x2 wave grid, 64x64 C per wave

  __shared__ __align__(16) unsigned char smem[32768];
  unsigned char* As = smem;           // [128][64] bf16, swizzled
  unsigned char* Bs = smem + 16384;

  f32x4 acc[4][4];
#pragma unroll
  for (int i = 0; i < 4; i++)
#pragma unroll
    for (int j = 0; j < 4; j++) acc[i][j] = (f32x4)0.f;

  for (int kt = 0; kt < 16; ++kt) {
    const int k0 = kt * 64;
#pragma unroll
    for (int ii = 0; ii < 4; ++ii) {
      int c = w * 4 + ii;                     // 16 chunks x 1KB per tile
      int p = c * 1024 + l * 16;              // linear LDS dest byte
      int ps = p ^ (((p >> 7) & 7) << 4);     // pre-swizzled source position
      int f = ps >> 1;                        // element index in tile
      int row = f >> 6, col = f & 63;
      gload16(A  + (size_t)(m0 + row) * 1024 + k0 + col, As + c * 1024);
      gload16(BT + (size_t)(n0 + row) * 1024 + k0 + col, Bs + c * 1024);
    }
    __syncthreads();   // drains vmcnt before barrier (compiler semantics)
#pragma unroll
    for (int kk = 0; kk < 2; ++kk) {
      bfv8 af[4], bf[4];
#pragma unroll
      for (int i = 0; i < 4; i++) {
        int row = wm * 64 + i * 16 + q4;
        int off = (row * 128 + kk * 64 + g * 16) ^ ((row & 7) << 4);
        af[i] = *(const bfv8*)(As + off);
      }
#pragma unroll
      for (int j = 0; j < 4; j++) {
        int row = wn * 64 + j * 16 + q4;
        int off = (row * 128 + kk * 64 + g * 16) ^ ((row & 7) << 4);
        bf[j] = *(const bfv8*)(Bs + off);
      }
#pragma unroll
      for (int i = 0; i < 4; i++)
#pragma unroll
        for (int j = 0; j < 4; j++)
          acc[i][j] = mfma16(af[i], bf[j], acc[i][j]);
    }
    __syncthreads();
  }

  // epilogue: C/D frag (m = ...+g*4+r, n-col = q4)
  const float scale = (mode == 0) ? 0.125f : 1.0f;
#pragma unroll
  for (int j = 0; j < 4; j++) {
    int n = n0 + wn * 64 + j * 16 + q4;
    float bv = bias[n];
#pragma unroll
    for (int i = 0; i < 4; i++) {
      int mb = m0 + wm * 64 + i * 16 + g * 4;
      if (mode == 2) {
        int bh = (mb >> 11) * 16 + (n >> 6);
        size_t base = ((size_t)bh * 64 + (n & 63)) * 2048 + (mb & 2047);
        short4v pk;
#pragma unroll
        for (int r = 0; r < 4; r++) pk[r] = f2bf(acc[i][j][r] + bv);
        *(short4v*)(o2 + base) = pk;
      } else if (mode == 3) {
#pragma unroll
        for (int r = 0; r < 4; r++)
          o3[(size_t)(mb + r) * 1024 + n] = acc[i][j][r] + bv;
      } else {
        short* O = mode == 0 ? o0 : o1;
        int bh = (mb >> 11) * 16 + (n >> 6);
#pragma unroll
        for (int r = 0; r < 4; r++)
          O[((size_t)bh * 2048 + ((mb + r) & 2047)) * 64 + (n & 63)] =
              f2bf((acc[i][j][r] + bv) * scale);
      }
    }
  }
}

// ---------------------------------------------------------------------------
// Kernel D: flash attention. grid = (S/128, B*H). 4 waves, 32 q-rows/wave.
// Swapped QK^T: st = mfma(K_frag, Q_frag) -> lane's col = q = lane&15,
// so online-softmax state (m, l) is lane-local (2 shuffles per reduce).
// P round-trips per-wave LDS (row stride 144B), then O^T = mfma(VT, P^T)
// so the alpha-rescale is also lane-local.
__global__ __launch_bounds__(256) void attn_fwd(
    const short* __restrict__ qg, const short* __restrict__ kg,
    const short* __restrict__ vtg, short* __restrict__ og) {
  const int tid = threadIdx.x, w = tid >> 6, l = tid & 63;
  const int g = l >> 4, q4 = l & 15;
  const int bh = blockIdx.y, b = bh >> 4, h = bh & 15;
  const short* qh  = qg  + (size_t)bh * 2048 * 64;
  const short* kh  = kg  + (size_t)bh * 2048 * 64;
  const short* vth = vtg + (size_t)bh * 64 * 2048;
  const int q0 = blockIdx.x * 128 + w * 32;

  __shared__ __align__(16) unsigned char smem[25600];
  unsigned char* Kl = smem;                       // [64 kv][64 d] swizzled
  unsigned char* Vl = smem + 8192;                // [64 e][64 kv] swizzled
  unsigned char* Pl = smem + 16384 + w * 2304;    // per-wave [16 q][stride 144B]

  bfv8 qf[2][2];   // q pre-scaled by 0.125 in projection
#pragma unroll
  for (int qm = 0; qm < 2; qm++)
#pragma unroll
    for (int kk = 0; kk < 2; kk++)
      qf[qm][kk] = *(const bfv8*)(qh + (size_t)(q0 + qm * 16 + q4) * 64 + kk * 32 + g * 8);

  f32x4 ot[2][4];
#pragma unroll
  for (int qm = 0; qm < 2; qm++)
#pragma unroll
    for (int n = 0; n < 4; n++) ot[qm][n] = (f32x4)0.f;
  float mst[2] = {-1e30f, -1e30f};
  float lst[2] = {0.f, 0.f};

  for (int t = 0; t < 32; ++t) {
    // stage K tile and VT tile, swizzled source (LDS dest linear)
#pragma unroll
    for (int ii = 0; ii < 2; ++ii) {
      int c = w + ii * 4;
      int p = c * 1024 + l * 16;
      int ps = p ^ (((p >> 7) & 7) << 4);
      int f = ps >> 1;
      gload16(kh + (size_t)t * 4096 + f, Kl + c * 1024);
      gload16(vth + (size_t)(f >> 6) * 2048 + t * 64 + (f & 63), Vl + c * 1024);
    }
    __syncthreads();

    bfv8 kf[4][2], vf[4][2];
#pragma unroll
    for (int n = 0; n < 4; n++)
#pragma unroll
      for (int kk = 0; kk < 2; kk++) {
        int row = n * 16 + q4;
        int off = (row * 128 + kk * 64 + g * 16) ^ ((row & 7) << 4);
        kf[n][kk] = *(const bfv8*)(Kl + off);
        vf[n][kk] = *(const bfv8*)(Vl + off);
      }

#pragma unroll
    for (int qm = 0; qm < 2; qm++) {
      f32x4 st[4];
#pragma unroll
      for (int n = 0; n < 4; n++) st[n] = (f32x4)0.f;
#pragma unroll
      for (int n = 0; n < 4; n++)
#pragma unroll
        for (int kk = 0; kk < 2; kk++)
          st[n] = mfma16(kf[n][kk], qf[qm][kk], st[n]);  // D[kv][q]

      // online softmax; lanes {q4, q4+16, q4+32, q4+48} together hold 64 kv
      float mt = st[0][0];
#pragma unroll
      for (int n = 0; n < 4; n++)
#pragma unroll
        for (int r = 0; r < 4; r++) mt = fmaxf(mt, st[n][r]);
      mt = fmaxf(mt, __shfl_xor(mt, 16));
      mt = fmaxf(mt, __shfl_xor(mt, 32));
      float mnew = fmaxf(mst[qm], mt);
      float alpha = __expf(mst[qm] - mnew);
      mst[qm] = mnew;
      float psum = 0.f;
      short4v pk[4];
#pragma unroll
      for (int n = 0; n < 4; n++)
#pragma unroll
        for (int r = 0; r < 4; r++) {
          float pv = __expf(st[n][r] - mnew);
          psum += pv;
          pk[n][r] = f2bf(pv);
        }
      psum += __shfl_xor(psum, 16);
      psum += __shfl_xor(psum, 32);
      lst[qm] = lst[qm] * alpha + psum;

      // P[q][kv] round-trip (intra-wave; DS pipe is in-order per wave)
#pragma unroll
      for (int n = 0; n < 4; n++)
        *(short4v*)(Pl + q4 * 144 + n * 32 + g * 8) = pk[n];
      asm volatile("" ::: "memory");
      bfv8 pf[2];
#pragma unroll
      for (int kk = 0; kk < 2; kk++)
        pf[kk] = *(const bfv8*)(Pl + q4 * 144 + kk * 64 + g * 16);

#pragma unroll
      for (int n = 0; n < 4; n++) {
#pragma unroll
        for (int r = 0; r < 4; r++) ot[qm][n][r] *= alpha;
#pragma unroll
        for (int kk = 0; kk < 2; kk++)
          ot[qm][n] = mfma16(vf[n][kk], pf[kk], ot[qm][n]);  // D[e][q]
      }
    }
    __syncthreads();
  }

  // epilogue: aws[b, q, h*64 + e] bf16; e = n*16 + g*4 + r, q = q0+qm*16+q4
#pragma unroll
  for (int qm = 0; qm < 2; qm++) {
    float inv = 1.0f / lst[qm];
    int qrow = q0 + qm * 16 + q4;
    size_t rb = ((size_t)b * 2048 + qrow) * 1024 + h * 64;
#pragma unroll
    for (int n = 0; n < 4; n++) {
      short4v pk;
#pragma unroll
      for (int r = 0; r < 4; r++) pk[r] = f2bf(ot[qm][n][r] * inv);
      *(short4v*)(og + rb + n * 16 + g * 4) = pk;
    }
  }
}

// ---------------------------------------------------------------------------
extern "C" void kernel_launch(void* const* d_in, const int* in_sizes, int n_in,
                              void* d_out, int out_size, void* d_ws, size_t ws_size,
                              hipStream_t stream) {
  const float* Query = (const float*)d_in[0];
  const float* Key   = (const float*)d_in[1];
  const float* Value = (const float*)d_in[2];
  const float* Wq    = (const float*)d_in[3];
  const float* bq    = (const float*)d_in[4];
  const float* Wk    = (const float*)d_in[5];
  const float* bk    = (const float*)d_in[6];
  const float* Wv    = (const float*)d_in[7];
  const float* bv    = (const float*)d_in[8];
  const float* Wo    = (const float*)d_in[9];
  const float* bo    = (const float*)d_in[10];
  float* out = (float*)d_out;

  short* ws   = (short*)d_ws;
  short* WT   = ws;                      // 4 x 1Mi bf16 = 8 MiB (WqT,WkT,WvT,WoT)
  short* Xbf  = ws + 4 * 1048576;        // [3][8192][1024] bf16 = 48 MiB
  short* qws  = Xbf + 3 * 8388608;       // [B*H][S][64] = 16 MiB
  short* kws  = qws + 8388608;
  short* vtws = kws + 8388608;           // [B*H][64][S]
  short* aws  = Xbf;                     // alias: Xbf dead after proj GEMMs

  hipLaunchKernelGGL(cvt_to_bf16, dim3(8192, 1, 1), dim3(256, 1, 1), 0, stream,
                     Query, Key, Value, Xbf);
  hipLaunchKernelGGL(transpose_w, dim3(4096, 4, 1), dim3(256, 1, 1), 0, stream,
                     Wq, Wk, Wv, Wo, WT);
  hipLaunchKernelGGL(gemm128, dim3(8, 64, 3), dim3(256, 1, 1), 0, stream,
                     Xbf, Xbf + 8388608, Xbf + 2 * 8388608, aws, WT,
                     bq, bk, bv, bo, qws, kws, vtws, out, 0);
  hipLaunchKernelGGL(attn_fwd, dim3(16, 64, 1), dim3(256, 1, 1), 0, stream,
                     qws, kws, vtws, aws);
  hipLaunchKernelGGL(gemm128, dim3(8, 64, 1), dim3(256, 1, 1), 0, stream,
                     Xbf, Xbf + 8388608, Xbf + 2 * 8388608, aws, WT,
                     bq, bk, bv, bo, qws, kws, vtws, out, 3);
}

// Round 3
// 263.624 us; speedup vs baseline: 1.1331x; 1.1331x over previous
//
#include <hip/hip_runtime.h>
#include <hip/hip_bf16.h>

// Problem constants: B=4, S=2048, DK=DV=1024, H=16, DKH=DVH=64.
// Harness dtypes: ALL inputs f32, output f32. Internal: bf16 MFMA, f32 accum.
// Softmax runs in exp2 domain: q is pre-scaled by 0.125*log2(e) at projection.

typedef __attribute__((ext_vector_type(8))) __bf16 bfv8;   // MFMA A/B frag (4 VGPR)
typedef __attribute__((ext_vector_type(4))) __bf16 bfv4;   // 8B packed bf16
typedef __attribute__((ext_vector_type(4))) float f32x4;   // MFMA C/D frag
typedef __attribute__((ext_vector_type(4))) short short4v; // 8B packed store
typedef unsigned int u32;

#define QSCALE 0.1803368801111244f  // 0.125 * log2(e)

#if __has_builtin(__builtin_amdgcn_exp2f)
#define EXP2(x) __builtin_amdgcn_exp2f(x)
#else
#define EXP2(x) __expf((x) * 0.6931471805599453f)
#endif

__device__ __forceinline__ f32x4 mfma16(bfv8 a, bfv8 b, f32x4 c) {
  return __builtin_amdgcn_mfma_f32_16x16x32_bf16(a, b, c, 0, 0, 0);
}

__device__ __forceinline__ void gload16(const void* g, void* l) {
  // async global->LDS, 16B per lane; LDS dest is wave-uniform base (+lane*16 in HW)
  __builtin_amdgcn_global_load_lds(
      (const __attribute__((address_space(1))) u32*)g,
      (__attribute__((address_space(3))) u32*)l, 16, 0, 0);
}

__device__ __forceinline__ short f2bf(float f) {  // round-to-nearest-even
  u32 u; __builtin_memcpy(&u, &f, 4);
  u += 0x7fffu + ((u >> 16) & 1u);
  return (short)(u >> 16);
}

// ---------------------------------------------------------------------------
// Kernel A: convert Q/K/V activations f32 -> bf16 into ws ([3][8192][1024]).
__global__ __launch_bounds__(256) void cvt_to_bf16(
    const float* __restrict__ Q, const float* __restrict__ K,
    const float* __restrict__ V, short* __restrict__ dst) {
  const size_t N = (size_t)8388608;  // 8192*1024
  size_t idx = (size_t)blockIdx.x * 256 + threadIdx.x;
  for (size_t c = idx; c < 3 * N / 4; c += (size_t)gridDim.x * 256) {
    size_t i = c * 4;
    const float* src = i < N ? Q + i : (i < 2 * N ? K + i - N : V + i - 2 * N);
    float4 v = *(const float4*)src;
    bfv4 o;
    o[0] = (__bf16)v.x; o[1] = (__bf16)v.y; o[2] = (__bf16)v.z; o[3] = (__bf16)v.w;
    *(bfv4*)(dst + i) = o;
  }
}

// ---------------------------------------------------------------------------
// Kernel B: transpose+convert weights into bf16 WT[mat][N=1024][K=1024].
//   mat 0..3 = WqT,WkT,WvT,WoT. Wq/Wk/Wv are [H=16][K=1024][64].
//   Coalesced both sides via 64x64 LDS tile. grid = (16 ktiles, 16, 4 mats);
//   blockIdx.y = head (mats 0-2) or n-tile (mat 3).
__global__ __launch_bounds__(256) void transpose_w(
    const float* __restrict__ Wq, const float* __restrict__ Wk,
    const float* __restrict__ Wv, const float* __restrict__ Wo,
    short* __restrict__ WT) {
  const int mat = blockIdx.z;
  const float* src = mat == 0 ? Wq : mat == 1 ? Wk : mat == 2 ? Wv : Wo;
  const int kt = blockIdx.x * 64;
  const int nt = blockIdx.y;
  const int tx = threadIdx.x & 15, ty = threadIdx.x >> 4;

  __shared__ __bf16 tile[64][68];  // +4 pad
#pragma unroll
  for (int p = 0; p < 4; ++p) {
    int k = p * 16 + ty, e0 = tx * 4;
    const float* sp = (mat < 3)
        ? src + (size_t)nt * 65536 + (size_t)(kt + k) * 64 + e0
        : src + (size_t)(kt + k) * 1024 + nt * 64 + e0;
    float4 v = *(const float4*)sp;
    bfv4 o;
    o[0] = (__bf16)v.x; o[1] = (__bf16)v.y; o[2] = (__bf16)v.z; o[3] = (__bf16)v.w;
    *(bfv4*)&tile[k][e0] = o;
  }
  __syncthreads();
#pragma unroll
  for (int p = 0; p < 4; ++p) {
    int e = p * 16 + ty, k0 = tx * 4;
    bfv4 o;
    o[0] = tile[k0][e]; o[1] = tile[k0 + 1][e];
    o[2] = tile[k0 + 2][e]; o[3] = tile[k0 + 3][e];
    *(bfv4*)(WT + (size_t)mat * 1048576 + (size_t)(nt * 64 + e) * 1024 + kt + k0) = o;
  }
}

// ---------------------------------------------------------------------------
// Kernel C: 128x128-tile GEMM  C = A[M x 1024] * WT[mode]^T + bias, K=1024.
// mode 0: q proj  -> q_ws[b,h,s,e]  scaled by QSCALE (fold 1/sqrt(64)*log2e)
// mode 1: k proj  -> k_ws[b,h,s,e]
// mode 2: v proj  -> vT_ws[b,h,e,s] (transposed for PV B-operand)
// mode 3: out proj-> d_out[m][n] (f32)
// LDS tiles [128 rows][64 k] bf16, XOR-swizzled: byte ^= ((row&7)<<4).
__global__ __launch_bounds__(256) void gemm128(
    const short* __restrict__ A0, const short* __restrict__ A1,
    const short* __restrict__ A2, const short* __restrict__ A3,
    const short* __restrict__ WT,
    const float* __restrict__ b0, const float* __restrict__ b1,
    const float* __restrict__ b2, const float* __restrict__ b3,
    short* __restrict__ o0, short* __restrict__ o1,
    short* __restrict__ o2, float* __restrict__ o3,
    int mode_base) {
  const int mode = mode_base + blockIdx.z;
  const short* A    = mode == 0 ? A0 : mode == 1 ? A1 : mode == 2 ? A2 : A3;
  const float* bias = mode == 0 ? b0 : mode == 1 ? b1 : mode == 2 ? b2 : b3;
  const short* BT   = WT + (size_t)mode * 1048576;

  const int m0 = blockIdx.y * 128, n0 = blockIdx.x * 128;
  const int tid = threadIdx.x, w = tid >> 6, l = tid & 63;
  const int g = l >> 4, q4 = l & 15;
  const int wm = w >> 1, wn = w & 1;   // 2x2 wave grid, 64x64 C per wave

  __shared__ __align__(16) unsigned char smem[32768];
  unsigned char* As = smem;           // [128][64] bf16, swizzled
  unsigned char* Bs = smem + 16384;

  f32x4 acc[4][4];
#pragma unroll
  for (int i = 0; i < 4; i++)
#pragma unroll
    for (int j = 0; j < 4; j++) acc[i][j] = (f32x4)0.f;

  for (int kt = 0; kt < 16; ++kt) {
    const int k0 = kt * 64;
#pragma unroll
    for (int ii = 0; ii < 4; ++ii) {
      int c = w * 4 + ii;                     // 16 chunks x 1KB per tile
      int p = c * 1024 + l * 16;              // linear LDS dest byte
      int ps = p ^ (((p >> 7) & 7) << 4);     // pre-swizzled source position
      int f = ps >> 1;                        // element index in tile
      int row = f >> 6, col = f & 63;
      gload16(A  + (size_t)(m0 + row) * 1024 + k0 + col, As + c * 1024);
      gload16(BT + (size_t)(n0 + row) * 1024 + k0 + col, Bs + c * 1024);
    }
    __syncthreads();
#pragma unroll
    for (int kk = 0; kk < 2; ++kk) {
      bfv8 af[4], bf[4];
#pragma unroll
      for (int i = 0; i < 4; i++) {
        int row = wm * 64 + i * 16 + q4;
        int off = (row * 128 + kk * 64 + g * 16) ^ ((row & 7) << 4);
        af[i] = *(const bfv8*)(As + off);
      }
#pragma unroll
      for (int j = 0; j < 4; j++) {
        int row = wn * 64 + j * 16 + q4;
        int off = (row * 128 + kk * 64 + g * 16) ^ ((row & 7) << 4);
        bf[j] = *(const bfv8*)(Bs + off);
      }
#pragma unroll
      for (int i = 0; i < 4; i++)
#pragma unroll
        for (int j = 0; j < 4; j++)
          acc[i][j] = mfma16(af[i], bf[j], acc[i][j]);
    }
    __syncthreads();
  }

  // epilogue: C/D frag (m = ...+g*4+r, n-col = q4)
  const float scale = (mode == 0) ? QSCALE : 1.0f;
#pragma unroll
  for (int j = 0; j < 4; j++) {
    int n = n0 + wn * 64 + j * 16 + q4;
    float bv = bias[n];
#pragma unroll
    for (int i = 0; i < 4; i++) {
      int mb = m0 + wm * 64 + i * 16 + g * 4;
      if (mode == 2) {
        int bh = (mb >> 11) * 16 + (n >> 6);
        size_t base = ((size_t)bh * 64 + (n & 63)) * 2048 + (mb & 2047);
        short4v pk;
#pragma unroll
        for (int r = 0; r < 4; r++) pk[r] = f2bf(acc[i][j][r] + bv);
        *(short4v*)(o2 + base) = pk;
      } else if (mode == 3) {
#pragma unroll
        for (int r = 0; r < 4; r++)
          o3[(size_t)(mb + r) * 1024 + n] = acc[i][j][r] + bv;
      } else {
        short* O = mode == 0 ? o0 : o1;
        int bh = (mb >> 11) * 16 + (n >> 6);
#pragma unroll
        for (int r = 0; r < 4; r++)
          O[((size_t)bh * 2048 + ((mb + r) & 2047)) * 64 + (n & 63)] =
              f2bf((acc[i][j][r] + bv) * scale);
      }
    }
  }
}

// ---------------------------------------------------------------------------
// Kernel D: flash attention. grid = (S/128, B*H). 4 waves, 32 q-rows/wave.
// Swapped QK^T: st = mfma(K_frag, Q_frag) -> lane's col = q = lane&15,
// so online-softmax state (m, l) is lane-local. Scores are in exp2 domain
// (q pre-scaled by QSCALE). T13 defer-rescale with THR=8.
__global__ __launch_bounds__(256) void attn_fwd(
    const short* __restrict__ qg, const short* __restrict__ kg,
    const short* __restrict__ vtg, short* __restrict__ og) {
  const int tid = threadIdx.x, w = tid >> 6, l = tid & 63;
  const int g = l >> 4, q4 = l & 15;
  const int bh = blockIdx.y, b = bh >> 4, h = bh & 15;
  const short* qh  = qg  + (size_t)bh * 131072;
  const short* kh  = kg  + (size_t)bh * 131072;
  const short* vth = vtg + (size_t)bh * 131072;
  const int q0 = blockIdx.x * 128 + w * 32;

  __shared__ __align__(16) unsigned char smem[25600];
  unsigned char* Kl = smem;                       // [64 kv][64 d] swizzled
  unsigned char* Vl = smem + 8192;                // [64 e][64 kv] swizzled
  unsigned char* Pl = smem + 16384 + w * 2304;    // per-wave [16 q][stride 144B]

  bfv8 qf[2][2];   // q pre-scaled by QSCALE in projection
#pragma unroll
  for (int qm = 0; qm < 2; qm++)
#pragma unroll
    for (int kk = 0; kk < 2; kk++)
      qf[qm][kk] = *(const bfv8*)(qh + (size_t)(q0 + qm * 16 + q4) * 64 + kk * 32 + g * 8);

  f32x4 ot[2][4];
#pragma unroll
  for (int qm = 0; qm < 2; qm++)
#pragma unroll
    for (int n = 0; n < 4; n++) ot[qm][n] = (f32x4)0.f;
  float mst[2] = {-3.0e38f, -3.0e38f};
  float lst[2] = {0.f, 0.f};

  for (int t = 0; t < 32; ++t) {
    // stage K tile and VT tile, swizzled source (LDS dest linear)
#pragma unroll
    for (int ii = 0; ii < 2; ++ii) {
      int c = w + ii * 4;
      int p = c * 1024 + l * 16;
      int ps = p ^ (((p >> 7) & 7) << 4);
      int f = ps >> 1;
      gload16(kh + (size_t)t * 4096 + f, Kl + c * 1024);
      gload16(vth + (size_t)(f >> 6) * 2048 + t * 64 + (f & 63), Vl + c * 1024);
    }
    __syncthreads();

    bfv8 kf[4][2], vf[4][2];
#pragma unroll
    for (int n = 0; n < 4; n++)
#pragma unroll
      for (int kk = 0; kk < 2; kk++) {
        int row = n * 16 + q4;
        int off = (row * 128 + kk * 64 + g * 16) ^ ((row & 7) << 4);
        kf[n][kk] = *(const bfv8*)(Kl + off);
        vf[n][kk] = *(const bfv8*)(Vl + off);
      }

#pragma unroll
    for (int qm = 0; qm < 2; qm++) {
      f32x4 st[4];
#pragma unroll
      for (int n = 0; n < 4; n++) st[n] = (f32x4)0.f;
#pragma unroll
      for (int n = 0; n < 4; n++)
#pragma unroll
        for (int kk = 0; kk < 2; kk++)
          st[n] = mfma16(kf[n][kk], qf[qm][kk], st[n]);  // D[kv][q], exp2 domain

      // tile max, pairwise tree (depth 4) then cross-group shuffles
      f32x4 ma, mb;
#pragma unroll
      for (int r = 0; r < 4; r++) {
        ma[r] = fmaxf(st[0][r], st[1][r]);
        mb[r] = fmaxf(st[2][r], st[3][r]);
      }
      float m0a = fmaxf(fmaxf(ma[0], ma[1]), fmaxf(ma[2], ma[3]));
      float m0b = fmaxf(fmaxf(mb[0], mb[1]), fmaxf(mb[2], mb[3]));
      float mt = fmaxf(m0a, m0b);
      mt = fmaxf(mt, __shfl_xor(mt, 16));
      mt = fmaxf(mt, __shfl_xor(mt, 32));

      // T13 defer-rescale: only rescale when tile max exceeds running max + 8
      if (__any(mt > mst[qm] + 8.0f)) {
        float mnew = fmaxf(mst[qm], mt);
        float alpha = EXP2(mst[qm] - mnew);
        mst[qm] = mnew;
        lst[qm] *= alpha;
#pragma unroll
        for (int n = 0; n < 4; n++)
#pragma unroll
          for (int r = 0; r < 4; r++) ot[qm][n][r] *= alpha;
      }
      const float m = mst[qm];

      bfv4 pk[4];
      f32x4 ps0;
#pragma unroll
      for (int r = 0; r < 4; r++) ps0[r] = 0.f;
#pragma unroll
      for (int n = 0; n < 4; n++)
#pragma unroll
        for (int r = 0; r < 4; r++) {
          float pv = EXP2(st[n][r] - m);
          ps0[r] += pv;
          pk[n][r] = (__bf16)pv;
        }
      float psum = (ps0[0] + ps0[1]) + (ps0[2] + ps0[3]);
      psum += __shfl_xor(psum, 16);
      psum += __shfl_xor(psum, 32);
      lst[qm] += psum;

      // P[q][kv] round-trip (intra-wave; DS pipe is in-order per wave)
#pragma unroll
      for (int n = 0; n < 4; n++)
        *(bfv4*)(Pl + q4 * 144 + n * 32 + g * 8) = pk[n];
      asm volatile("" ::: "memory");
      bfv8 pf[2];
#pragma unroll
      for (int kk = 0; kk < 2; kk++)
        pf[kk] = *(const bfv8*)(Pl + q4 * 144 + kk * 64 + g * 16);

#pragma unroll
      for (int n = 0; n < 4; n++)
#pragma unroll
        for (int kk = 0; kk < 2; kk++)
          ot[qm][n] = mfma16(vf[n][kk], pf[kk], ot[qm][n]);  // D[e][q]
    }
    __syncthreads();
  }

  // epilogue: aws[b, q, h*64 + e] bf16; e = n*16 + g*4 + r, q = q0+qm*16+q4
#pragma unroll
  for (int qm = 0; qm < 2; qm++) {
    float inv = 1.0f / lst[qm];
    int qrow = q0 + qm * 16 + q4;
    size_t rb = ((size_t)b * 2048 + qrow) * 1024 + h * 64;
#pragma unroll
    for (int n = 0; n < 4; n++) {
      short4v pk;
#pragma unroll
      for (int r = 0; r < 4; r++) pk[r] = f2bf(ot[qm][n][r] * inv);
      *(short4v*)(og + rb + n * 16 + g * 4) = pk;
    }
  }
}

// ---------------------------------------------------------------------------
extern "C" void kernel_launch(void* const* d_in, const int* in_sizes, int n_in,
                              void* d_out, int out_size, void* d_ws, size_t ws_size,
                              hipStream_t stream) {
  const float* Query = (const float*)d_in[0];
  const float* Key   = (const float*)d_in[1];
  const float* Value = (const float*)d_in[2];
  const float* Wq    = (const float*)d_in[3];
  const float* bq    = (const float*)d_in[4];
  const float* Wk    = (const float*)d_in[5];
  const float* bk    = (const float*)d_in[6];
  const float* Wv    = (const float*)d_in[7];
  const float* bv    = (const float*)d_in[8];
  const float* Wo    = (const float*)d_in[9];
  const float* bo    = (const float*)d_in[10];
  float* out = (float*)d_out;

  short* ws   = (short*)d_ws;
  short* WT   = ws;                      // 4 x 1Mi bf16 = 8 MiB (WqT,WkT,WvT,WoT)
  short* Xbf  = ws + 4 * 1048576;        // [3][8192][1024] bf16 = 48 MiB
  short* qws  = Xbf + 3 * 8388608;       // [B*H][S][64] = 16 MiB
  short* kws  = qws + 8388608;
  short* vtws = kws + 8388608;           // [B*H][64][S]
  short* aws  = Xbf;                     // alias: Xbf dead after proj GEMMs

  hipLaunchKernelGGL(cvt_to_bf16, dim3(8192, 1, 1), dim3(256, 1, 1), 0, stream,
                     Query, Key, Value, Xbf);
  hipLaunchKernelGGL(transpose_w, dim3(16, 16, 4), dim3(256, 1, 1), 0, stream,
                     Wq, Wk, Wv, Wo, WT);
  hipLaunchKernelGGL(gemm128, dim3(8, 64, 3), dim3(256, 1, 1), 0, stream,
                     Xbf, Xbf + 8388608, Xbf + 2 * 8388608, aws, WT,
                     bq, bk, bv, bo, qws, kws, vtws, out, 0);
  hipLaunchKernelGGL(attn_fwd, dim3(16, 64, 1), dim3(256, 1, 1), 0, stream,
                     qws, kws, vtws, aws);
  hipLaunchKernelGGL(gemm128, dim3(8, 64, 1), dim3(256, 1, 1), 0, stream,
                     Xbf, Xbf + 8388608, Xbf + 2 * 8388608, aws, WT,
                     bq, bk, bv, bo, qws, kws, vtws, out, 3);
}

// Round 4
// 258.056 us; speedup vs baseline: 1.1576x; 1.0216x over previous
//
#include <hip/hip_runtime.h>
#include <hip/hip_bf16.h>

// Problem constants: B=4, S=2048, DK=DV=1024, H=16, DKH=DVH=64.
// Harness dtypes: ALL inputs f32, output f32. Internal: bf16 MFMA, f32 accum.
// Softmax runs in exp2 domain: q is pre-scaled by 0.125*log2(e) at projection.

typedef __attribute__((ext_vector_type(8))) __bf16 bfv8;   // MFMA A/B frag (4 VGPR)
typedef __attribute__((ext_vector_type(4))) __bf16 bfv4;   // 8B packed bf16
typedef __attribute__((ext_vector_type(4))) float f32x4;   // MFMA C/D frag
typedef __attribute__((ext_vector_type(4))) short short4v; // 8B packed store
typedef unsigned int u32;

#define QSCALE 0.1803368801111244f  // 0.125 * log2(e)

#if __has_builtin(__builtin_amdgcn_exp2f)
#define EXP2(x) __builtin_amdgcn_exp2f(x)
#else
#define EXP2(x) __expf((x) * 0.6931471805599453f)
#endif

__device__ __forceinline__ f32x4 mfma16(bfv8 a, bfv8 b, f32x4 c) {
  return __builtin_amdgcn_mfma_f32_16x16x32_bf16(a, b, c, 0, 0, 0);
}

__device__ __forceinline__ void gload16(const void* g, void* l) {
  // async global->LDS, 16B per lane; LDS dest is wave-uniform base (+lane*16 in HW)
  __builtin_amdgcn_global_load_lds(
      (const __attribute__((address_space(1))) u32*)g,
      (__attribute__((address_space(3))) u32*)l, 16, 0, 0);
}

__device__ __forceinline__ short f2bf(float f) {  // round-to-nearest-even
  u32 u; __builtin_memcpy(&u, &f, 4);
  u += 0x7fffu + ((u >> 16) & 1u);
  return (short)(u >> 16);
}

// ---------------------------------------------------------------------------
// Kernel A: convert Q/K/V activations f32 -> bf16 into ws ([3][8192][1024]).
__global__ __launch_bounds__(256) void cvt_to_bf16(
    const float* __restrict__ Q, const float* __restrict__ K,
    const float* __restrict__ V, short* __restrict__ dst) {
  const size_t N = (size_t)8388608;  // 8192*1024
  size_t idx = (size_t)blockIdx.x * 256 + threadIdx.x;
  for (size_t c = idx; c < 3 * N / 4; c += (size_t)gridDim.x * 256) {
    size_t i = c * 4;
    const float* src = i < N ? Q + i : (i < 2 * N ? K + i - N : V + i - 2 * N);
    float4 v = *(const float4*)src;
    bfv4 o;
    o[0] = (__bf16)v.x; o[1] = (__bf16)v.y; o[2] = (__bf16)v.z; o[3] = (__bf16)v.w;
    *(bfv4*)(dst + i) = o;
  }
}

// ---------------------------------------------------------------------------
// Kernel B: transpose+convert weights into bf16 WT[mat][N=1024][K=1024].
//   mat 0..3 = WqT,WkT,WvT,WoT. Wq/Wk/Wv are [H=16][K=1024][64].
//   Coalesced both sides via 64x64 LDS tile.
__global__ __launch_bounds__(256) void transpose_w(
    const float* __restrict__ Wq, const float* __restrict__ Wk,
    const float* __restrict__ Wv, const float* __restrict__ Wo,
    short* __restrict__ WT) {
  const int mat = blockIdx.z;
  const float* src = mat == 0 ? Wq : mat == 1 ? Wk : mat == 2 ? Wv : Wo;
  const int kt = blockIdx.x * 64;
  const int nt = blockIdx.y;
  const int tx = threadIdx.x & 15, ty = threadIdx.x >> 4;

  __shared__ __bf16 tile[64][68];  // +4 pad
#pragma unroll
  for (int p = 0; p < 4; ++p) {
    int k = p * 16 + ty, e0 = tx * 4;
    const float* sp = (mat < 3)
        ? src + (size_t)nt * 65536 + (size_t)(kt + k) * 64 + e0
        : src + (size_t)(kt + k) * 1024 + nt * 64 + e0;
    float4 v = *(const float4*)sp;
    bfv4 o;
    o[0] = (__bf16)v.x; o[1] = (__bf16)v.y; o[2] = (__bf16)v.z; o[3] = (__bf16)v.w;
    *(bfv4*)&tile[k][e0] = o;
  }
  __syncthreads();
#pragma unroll
  for (int p = 0; p < 4; ++p) {
    int e = p * 16 + ty, k0 = tx * 4;
    bfv4 o;
    o[0] = tile[k0][e]; o[1] = tile[k0 + 1][e];
    o[2] = tile[k0 + 2][e]; o[3] = tile[k0 + 3][e];
    *(bfv4*)(WT + (size_t)mat * 1048576 + (size_t)(nt * 64 + e) * 1024 + kt + k0) = o;
  }
}

// ---------------------------------------------------------------------------
// Kernel C: 128x128-tile GEMM  C = A[M x 1024] * WT[mode]^T + bias, K=1024.
// mode 0: q proj  -> q_ws[b,h,s,e]  scaled by QSCALE (fold 1/sqrt(64)*log2e)
// mode 1: k proj  -> k_ws[b,h,s,e]
// mode 2: v proj  -> vT_ws[b,h,e,s] (transposed for PV B-operand)
// mode 3: out proj-> d_out[m][n] (f32)
// LDS tiles [128 rows][64 k] bf16, XOR-swizzled: byte ^= ((row&7)<<4).
__global__ __launch_bounds__(256) void gemm128(
    const short* __restrict__ A0, const short* __restrict__ A1,
    const short* __restrict__ A2, const short* __restrict__ A3,
    const short* __restrict__ WT,
    const float* __restrict__ b0, const float* __restrict__ b1,
    const float* __restrict__ b2, const float* __restrict__ b3,
    short* __restrict__ o0, short* __restrict__ o1,
    short* __restrict__ o2, float* __restrict__ o3,
    int mode_base) {
  const int mode = mode_base + blockIdx.z;
  const short* A    = mode == 0 ? A0 : mode == 1 ? A1 : mode == 2 ? A2 : A3;
  const float* bias = mode == 0 ? b0 : mode == 1 ? b1 : mode == 2 ? b2 : b3;
  const short* BT   = WT + (size_t)mode * 1048576;

  const int m0 = blockIdx.y * 128, n0 = blockIdx.x * 128;
  const int tid = threadIdx.x, w = tid >> 6, l = tid & 63;
  const int g = l >> 4, q4 = l & 15;
  const int wm = w >> 1, wn = w & 1;   // 2x2 wave grid, 64x64 C per wave

  __shared__ __align__(16) unsigned char smem[32768];
  unsigned char* As = smem;           // [128][64] bf16, swizzled
  unsigned char* Bs = smem + 16384;

  f32x4 acc[4][4];
#pragma unroll
  for (int i = 0; i < 4; i++)
#pragma unroll
    for (int j = 0; j < 4; j++) acc[i][j] = (f32x4)0.f;

  for (int kt = 0; kt < 16; ++kt) {
    const int k0 = kt * 64;
#pragma unroll
    for (int ii = 0; ii < 4; ++ii) {
      int c = w * 4 + ii;                     // 16 chunks x 1KB per tile
      int p = c * 1024 + l * 16;              // linear LDS dest byte
      int ps = p ^ (((p >> 7) & 7) << 4);     // pre-swizzled source position
      int f = ps >> 1;                        // element index in tile
      int row = f >> 6, col = f & 63;
      gload16(A  + (size_t)(m0 + row) * 1024 + k0 + col, As + c * 1024);
      gload16(BT + (size_t)(n0 + row) * 1024 + k0 + col, Bs + c * 1024);
    }
    __syncthreads();
#pragma unroll
    for (int kk = 0; kk < 2; ++kk) {
      bfv8 af[4], bf[4];
#pragma unroll
      for (int i = 0; i < 4; i++) {
        int row = wm * 64 + i * 16 + q4;
        int off = (row * 128 + kk * 64 + g * 16) ^ ((row & 7) << 4);
        af[i] = *(const bfv8*)(As + off);
      }
#pragma unroll
      for (int j = 0; j < 4; j++) {
        int row = wn * 64 + j * 16 + q4;
        int off = (row * 128 + kk * 64 + g * 16) ^ ((row & 7) << 4);
        bf[j] = *(const bfv8*)(Bs + off);
      }
#pragma unroll
      for (int i = 0; i < 4; i++)
#pragma unroll
        for (int j = 0; j < 4; j++)
          acc[i][j] = mfma16(af[i], bf[j], acc[i][j]);
    }
    __syncthreads();
  }

  // epilogue: C/D frag (m = ...+g*4+r, n-col = q4)
  const float scale = (mode == 0) ? QSCALE : 1.0f;
#pragma unroll
  for (int j = 0; j < 4; j++) {
    int n = n0 + wn * 64 + j * 16 + q4;
    float bv = bias[n];
#pragma unroll
    for (int i = 0; i < 4; i++) {
      int mb = m0 + wm * 64 + i * 16 + g * 4;
      if (mode == 2) {
        int bh = (mb >> 11) * 16 + (n >> 6);
        size_t base = ((size_t)bh * 64 + (n & 63)) * 2048 + (mb & 2047);
        short4v pk;
#pragma unroll
        for (int r = 0; r < 4; r++) pk[r] = f2bf(acc[i][j][r] + bv);
        *(short4v*)(o2 + base) = pk;
      } else if (mode == 3) {
#pragma unroll
        for (int r = 0; r < 4; r++)
          o3[(size_t)(mb + r) * 1024 + n] = acc[i][j][r] + bv;
      } else {
        short* O = mode == 0 ? o0 : o1;
        int bh = (mb >> 11) * 16 + (n >> 6);
#pragma unroll
        for (int r = 0; r < 4; r++)
          O[((size_t)bh * 2048 + ((mb + r) & 2047)) * 64 + (n & 63)] =
              f2bf((acc[i][j][r] + bv) * scale);
      }
    }
  }
}

// ---------------------------------------------------------------------------
// Kernel D: flash attention, double-buffered async staging (counted vmcnt).
// grid = (S/128, B*H). 4 waves, 32 q-rows/wave. Swapped QK^T (lane q = l&15).
// exp2-domain softmax, T13 defer-rescale, T5 setprio around MFMA clusters.
// LDS 40960B: K/V dbuf 2x16KB + per-wave P 2KB (stride 128B, XOR-swizzled,
// conflict-free write 8B / read 16B).
__global__ __launch_bounds__(256) void attn_fwd(
    const short* __restrict__ qg, const short* __restrict__ kg,
    const short* __restrict__ vtg, short* __restrict__ og) {
  const int tid = threadIdx.x, w = tid >> 6, l = tid & 63;
  const int g = l >> 4, q4 = l & 15;
  const int bh = blockIdx.y, b = bh >> 4, h = bh & 15;
  const short* qh  = qg  + (size_t)bh * 131072;
  const short* kh  = kg  + (size_t)bh * 131072;
  const short* vth = vtg + (size_t)bh * 131072;
  const int q0 = blockIdx.x * 128 + w * 32;

  __shared__ __align__(16) unsigned char smem[40960];
  unsigned char* Pl = smem + 32768 + w * 2048;   // per-wave [16 q][128B] swizzled

  bfv8 qf[2][2];   // q pre-scaled by QSCALE in projection
#pragma unroll
  for (int qm = 0; qm < 2; qm++)
#pragma unroll
    for (int kk = 0; kk < 2; kk++)
      qf[qm][kk] = *(const bfv8*)(qh + (size_t)(q0 + qm * 16 + q4) * 64 + kk * 32 + g * 8);
  asm volatile("" ::: "memory");   // pin q loads before the pipelined region
  __syncthreads();                 // drains vmcnt -> clean counter state

  // staging chunk geometry (per wave: 2 K chunks + 2 V chunks = 4 VMEM/tile)
  int cA = w, cB = w + 4;
  int pA = cA * 1024 + l * 16, pB = cB * 1024 + l * 16;
  int fA = (pA ^ (((pA >> 7) & 7) << 4)) >> 1;   // pre-swizzled source elem
  int fB = (pB ^ (((pB >> 7) & 7) << 4)) >> 1;

  // prologue: stage tile 0 into buffer 0
  {
    unsigned char* Kb = smem;
    gload16(kh + fA, Kb + cA * 1024);
    gload16(vth + (size_t)(fA >> 6) * 2048 + (fA & 63), Kb + 8192 + cA * 1024);
    gload16(kh + fB, Kb + cB * 1024);
    gload16(vth + (size_t)(fB >> 6) * 2048 + (fB & 63), Kb + 8192 + cB * 1024);
  }

  f32x4 ot[2][4];
#pragma unroll
  for (int qm = 0; qm < 2; qm++)
#pragma unroll
    for (int n = 0; n < 4; n++) ot[qm][n] = (f32x4)0.f;
  float mst[2] = {-3.0e38f, -3.0e38f};
  float lst[2] = {0.f, 0.f};

  for (int t = 0; t < 32; ++t) {
    unsigned char* cur = smem + (t & 1) * 16384;
    if (t < 31) {
      unsigned char* nxt = smem + ((t + 1) & 1) * 16384;
      size_t toff = (size_t)(t + 1) * 4096;
      int tcol = (t + 1) * 64;
      gload16(kh + toff + fA, nxt + cA * 1024);
      gload16(vth + (size_t)(fA >> 6) * 2048 + tcol + (fA & 63), nxt + 8192 + cA * 1024);
      gload16(kh + toff + fB, nxt + cB * 1024);
      gload16(vth + (size_t)(fB >> 6) * 2048 + tcol + (fB & 63), nxt + 8192 + cB * 1024);
      asm volatile("s_waitcnt vmcnt(4)" ::: "memory");  // cur complete, nxt in flight
    } else {
      asm volatile("s_waitcnt vmcnt(0)" ::: "memory");
    }
    __builtin_amdgcn_s_barrier();   // all waves' cur loads complete

    bfv8 kf[4][2], vf[4][2];
#pragma unroll
    for (int n = 0; n < 4; n++)
#pragma unroll
      for (int kk = 0; kk < 2; kk++) {
        int row = n * 16 + q4;
        int off = (row * 128 + kk * 64 + g * 16) ^ ((row & 7) << 4);
        kf[n][kk] = *(const bfv8*)(cur + off);
        vf[n][kk] = *(const bfv8*)(cur + 8192 + off);
      }

#pragma unroll
    for (int qm = 0; qm < 2; qm++) {
      f32x4 st[4];
#pragma unroll
      for (int n = 0; n < 4; n++) st[n] = (f32x4)0.f;
      __builtin_amdgcn_s_setprio(1);
#pragma unroll
      for (int n = 0; n < 4; n++)
#pragma unroll
        for (int kk = 0; kk < 2; kk++)
          st[n] = mfma16(kf[n][kk], qf[qm][kk], st[n]);  // D[kv][q], exp2 domain
      __builtin_amdgcn_s_setprio(0);

      // tile max, pairwise tree then cross-group shuffles
      f32x4 ma, mb;
#pragma unroll
      for (int r = 0; r < 4; r++) {
        ma[r] = fmaxf(st[0][r], st[1][r]);
        mb[r] = fmaxf(st[2][r], st[3][r]);
      }
      float m0a = fmaxf(fmaxf(ma[0], ma[1]), fmaxf(ma[2], ma[3]));
      float m0b = fmaxf(fmaxf(mb[0], mb[1]), fmaxf(mb[2], mb[3]));
      float mt = fmaxf(m0a, m0b);
      mt = fmaxf(mt, __shfl_xor(mt, 16));
      mt = fmaxf(mt, __shfl_xor(mt, 32));

      // T13 defer-rescale: only rescale when tile max exceeds running max + 8
      if (__any(mt > mst[qm] + 8.0f)) {
        float mnew = fmaxf(mst[qm], mt);
        float alpha = EXP2(mst[qm] - mnew);
        mst[qm] = mnew;
        lst[qm] *= alpha;
#pragma unroll
        for (int n = 0; n < 4; n++)
#pragma unroll
          for (int r = 0; r < 4; r++) ot[qm][n][r] *= alpha;
      }
      const float m = mst[qm];

      bfv4 pk[4];
      f32x4 ps0;
#pragma unroll
      for (int r = 0; r < 4; r++) ps0[r] = 0.f;
#pragma unroll
      for (int n = 0; n < 4; n++)
#pragma unroll
        for (int r = 0; r < 4; r++) {
          float pv = EXP2(st[n][r] - m);
          ps0[r] += pv;
          pk[n][r] = (__bf16)pv;
        }
      float psum = (ps0[0] + ps0[1]) + (ps0[2] + ps0[3]);
      psum += __shfl_xor(psum, 16);
      psum += __shfl_xor(psum, 32);
      lst[qm] += psum;

      // P round-trip, conflict-free swizzled layout [q][kv^swz], intra-wave
      const int swz = (q4 & 7) << 4;
#pragma unroll
      for (int n = 0; n < 4; n++)
        *(bfv4*)(Pl + q4 * 128 + ((n * 32 + g * 8) ^ swz)) = pk[n];
      asm volatile("" ::: "memory");
      bfv8 pf[2];
#pragma unroll
      for (int kk = 0; kk < 2; kk++)
        pf[kk] = *(const bfv8*)(Pl + q4 * 128 + ((kk * 64 + g * 16) ^ swz));

      __builtin_amdgcn_s_setprio(1);
#pragma unroll
      for (int n = 0; n < 4; n++)
#pragma unroll
        for (int kk = 0; kk < 2; kk++)
          ot[qm][n] = mfma16(vf[n][kk], pf[kk], ot[qm][n]);  // D[e][q]
      __builtin_amdgcn_s_setprio(0);
    }
    asm volatile("s_waitcnt lgkmcnt(0)" ::: "memory");
    __builtin_amdgcn_s_barrier();   // all waves done reading cur
  }

  // epilogue: aws[b, q, h*64 + e] bf16; e = n*16 + g*4 + r, q = q0+qm*16+q4
#pragma unroll
  for (int qm = 0; qm < 2; qm++) {
    float inv = 1.0f / lst[qm];
    int qrow = q0 + qm * 16 + q4;
    size_t rb = ((size_t)b * 2048 + qrow) * 1024 + h * 64;
#pragma unroll
    for (int n = 0; n < 4; n++) {
      bfv4 pk;
#pragma unroll
      for (int r = 0; r < 4; r++) pk[r] = (__bf16)(ot[qm][n][r] * inv);
      *(bfv4*)(og + rb + n * 16 + g * 4) = pk;
    }
  }
}

// ---------------------------------------------------------------------------
extern "C" void kernel_launch(void* const* d_in, const int* in_sizes, int n_in,
                              void* d_out, int out_size, void* d_ws, size_t ws_size,
                              hipStream_t stream) {
  const float* Query = (const float*)d_in[0];
  const float* Key   = (const float*)d_in[1];
  const float* Value = (const float*)d_in[2];
  const float* Wq    = (const float*)d_in[3];
  const float* bq    = (const float*)d_in[4];
  const float* Wk    = (const float*)d_in[5];
  const float* bk    = (const float*)d_in[6];
  const float* Wv    = (const float*)d_in[7];
  const float* bv    = (const float*)d_in[8];
  const float* Wo    = (const float*)d_in[9];
  const float* bo    = (const float*)d_in[10];
  float* out = (float*)d_out;

  short* ws   = (short*)d_ws;
  short* WT   = ws;                      // 4 x 1Mi bf16 = 8 MiB (WqT,WkT,WvT,WoT)
  short* Xbf  = ws + 4 * 1048576;        // [3][8192][1024] bf16 = 48 MiB
  short* qws  = Xbf + 3 * 8388608;       // [B*H][S][64] = 16 MiB
  short* kws  = qws + 8388608;
  short* vtws = kws + 8388608;           // [B*H][64][S]
  short* aws  = Xbf;                     // alias: Xbf dead after proj GEMMs

  hipLaunchKernelGGL(cvt_to_bf16, dim3(8192, 1, 1), dim3(256, 1, 1), 0, stream,
                     Query, Key, Value, Xbf);
  hipLaunchKernelGGL(transpose_w, dim3(16, 16, 4), dim3(256, 1, 1), 0, stream,
                     Wq, Wk, Wv, Wo, WT);
  hipLaunchKernelGGL(gemm128, dim3(8, 64, 3), dim3(256, 1, 1), 0, stream,
                     Xbf, Xbf + 8388608, Xbf + 2 * 8388608, aws, WT,
                     bq, bk, bv, bo, qws, kws, vtws, out, 0);
  hipLaunchKernelGGL(attn_fwd, dim3(16, 64, 1), dim3(256, 1, 1), 0, stream,
                     qws, kws, vtws, aws);
  hipLaunchKernelGGL(gemm128, dim3(8, 64, 1), dim3(256, 1, 1), 0, stream,
                     Xbf, Xbf + 8388608, Xbf + 2 * 8388608, aws, WT,
                     bq, bk, bv, bo, qws, kws, vtws, out, 3);
}

// Round 6
// 238.882 us; speedup vs baseline: 1.2505x; 1.0803x over previous
//
#include <hip/hip_runtime.h>
#include <hip/hip_bf16.h>

// Problem constants: B=4, S=2048, DK=DV=1024, H=16, DKH=DVH=64.
// Harness dtypes: ALL inputs f32, output f32. Internal: bf16 MFMA, f32 accum.
// Softmax runs in exp2 domain: q is pre-scaled by 0.125*log2(e) at projection.

typedef __attribute__((ext_vector_type(8))) __bf16 bfv8;    // MFMA A/B frag (4 VGPR)
typedef __attribute__((ext_vector_type(4))) __bf16 bfv4;    // 8B packed bf16
typedef __attribute__((ext_vector_type(4))) float f32x4;    // 16x16 C/D frag
typedef __attribute__((ext_vector_type(16))) float f32x16;  // 32x32 C/D frag
typedef __attribute__((ext_vector_type(4))) short short4v;
typedef __attribute__((ext_vector_type(4))) unsigned int u32x4;
typedef unsigned int u32;

#define QSCALE 0.1803368801111244f  // 0.125 * log2(e)

#if __has_builtin(__builtin_amdgcn_exp2f)
#define EXP2(x) __builtin_amdgcn_exp2f(x)
#else
#define EXP2(x) __expf((x) * 0.6931471805599453f)
#endif

__device__ __forceinline__ f32x4 mfma16(bfv8 a, bfv8 b, f32x4 c) {
  return __builtin_amdgcn_mfma_f32_16x16x32_bf16(a, b, c, 0, 0, 0);
}
__device__ __forceinline__ f32x16 mfma32(bfv8 a, bfv8 b, f32x16 c) {
  return __builtin_amdgcn_mfma_f32_32x32x16_bf16(a, b, c, 0, 0, 0);
}

__device__ __forceinline__ void gload16(const void* g, void* l) {
  // async global->LDS, 16B per lane; LDS dest is wave-uniform base (+lane*16 in HW)
  __builtin_amdgcn_global_load_lds(
      (const __attribute__((address_space(1))) u32*)g,
      (__attribute__((address_space(3))) u32*)l, 16, 0, 0);
}

__device__ __forceinline__ short f2bf(float f) {  // round-to-nearest-even
  u32 u; __builtin_memcpy(&u, &f, 4);
  u += 0x7fffu + ((u >> 16) & 1u);
  return (short)(u >> 16);
}

__device__ __forceinline__ u32 cvtpk(float a, float b) {  // (lo=a, hi=b) bf16 pair
  u32 d;
  asm("v_cvt_pk_bf16_f32 %0, %1, %2" : "=v"(d) : "v"(a), "v"(b));
  return d;
}

// ---------------------------------------------------------------------------
// Kernel A: convert Q/K/V activations f32 -> bf16 into ws ([3][8192][1024]).
__global__ __launch_bounds__(256) void cvt_to_bf16(
    const float* __restrict__ Q, const float* __restrict__ K,
    const float* __restrict__ V, short* __restrict__ dst) {
  const size_t N = (size_t)8388608;  // 8192*1024
  size_t idx = (size_t)blockIdx.x * 256 + threadIdx.x;
  for (size_t c = idx; c < 3 * N / 4; c += (size_t)gridDim.x * 256) {
    size_t i = c * 4;
    const float* src = i < N ? Q + i : (i < 2 * N ? K + i - N : V + i - 2 * N);
    float4 v = *(const float4*)src;
    bfv4 o;
    o[0] = (__bf16)v.x; o[1] = (__bf16)v.y; o[2] = (__bf16)v.z; o[3] = (__bf16)v.w;
    *(bfv4*)(dst + i) = o;
  }
}

// ---------------------------------------------------------------------------
// Kernel B: transpose+convert weights into bf16 WT[mat][N=1024][K=1024].
__global__ __launch_bounds__(256) void transpose_w(
    const float* __restrict__ Wq, const float* __restrict__ Wk,
    const float* __restrict__ Wv, const float* __restrict__ Wo,
    short* __restrict__ WT) {
  const int mat = blockIdx.z;
  const float* src = mat == 0 ? Wq : mat == 1 ? Wk : mat == 2 ? Wv : Wo;
  const int kt = blockIdx.x * 64;
  const int nt = blockIdx.y;
  const int tx = threadIdx.x & 15, ty = threadIdx.x >> 4;

  __shared__ __bf16 tile[64][68];  // +4 pad
#pragma unroll
  for (int p = 0; p < 4; ++p) {
    int k = p * 16 + ty, e0 = tx * 4;
    const float* sp = (mat < 3)
        ? src + (size_t)nt * 65536 + (size_t)(kt + k) * 64 + e0
        : src + (size_t)(kt + k) * 1024 + nt * 64 + e0;
    float4 v = *(const float4*)sp;
    bfv4 o;
    o[0] = (__bf16)v.x; o[1] = (__bf16)v.y; o[2] = (__bf16)v.z; o[3] = (__bf16)v.w;
    *(bfv4*)&tile[k][e0] = o;
  }
  __syncthreads();
#pragma unroll
  for (int p = 0; p < 4; ++p) {
    int e = p * 16 + ty, k0 = tx * 4;
    bfv4 o;
    o[0] = tile[k0][e]; o[1] = tile[k0 + 1][e];
    o[2] = tile[k0 + 2][e]; o[3] = tile[k0 + 3][e];
    *(bfv4*)(WT + (size_t)mat * 1048576 + (size_t)(nt * 64 + e) * 1024 + kt + k0) = o;
  }
}

// ---------------------------------------------------------------------------
// Kernel C: 128x128-tile GEMM  C = A[M x 1024] * WT[mode]^T + bias, K=1024.
// (unchanged — proven correct)
__global__ __launch_bounds__(256) void gemm128(
    const short* __restrict__ A0, const short* __restrict__ A1,
    const short* __restrict__ A2, const short* __restrict__ A3,
    const short* __restrict__ WT,
    const float* __restrict__ b0, const float* __restrict__ b1,
    const float* __restrict__ b2, const float* __restrict__ b3,
    short* __restrict__ o0, short* __restrict__ o1,
    short* __restrict__ o2, float* __restrict__ o3,
    int mode_base) {
  const int mode = mode_base + blockIdx.z;
  const short* A    = mode == 0 ? A0 : mode == 1 ? A1 : mode == 2 ? A2 : A3;
  const float* bias = mode == 0 ? b0 : mode == 1 ? b1 : mode == 2 ? b2 : b3;
  const short* BT   = WT + (size_t)mode * 1048576;

  const int m0 = blockIdx.y * 128, n0 = blockIdx.x * 128;
  const int tid = threadIdx.x, w = tid >> 6, l = tid & 63;
  const int g = l >> 4, q4 = l & 15;
  const int wm = w >> 1, wn = w & 1;

  __shared__ __align__(16) unsigned char smem[32768];
  unsigned char* As = smem;
  unsigned char* Bs = smem + 16384;

  f32x4 acc[4][4];
#pragma unroll
  for (int i = 0; i < 4; i++)
#pragma unroll
    for (int j = 0; j < 4; j++) acc[i][j] = (f32x4)0.f;

  for (int kt = 0; kt < 16; ++kt) {
    const int k0 = kt * 64;
#pragma unroll
    for (int ii = 0; ii < 4; ++ii) {
      int c = w * 4 + ii;
      int p = c * 1024 + l * 16;
      int ps = p ^ (((p >> 7) & 7) << 4);
      int f = ps >> 1;
      int row = f >> 6, col = f & 63;
      gload16(A  + (size_t)(m0 + row) * 1024 + k0 + col, As + c * 1024);
      gload16(BT + (size_t)(n0 + row) * 1024 + k0 + col, Bs + c * 1024);
    }
    __syncthreads();
#pragma unroll
    for (int kk = 0; kk < 2; ++kk) {
      bfv8 af[4], bf[4];
#pragma unroll
      for (int i = 0; i < 4; i++) {
        int row = wm * 64 + i * 16 + q4;
        int off = (row * 128 + kk * 64 + g * 16) ^ ((row & 7) << 4);
        af[i] = *(const bfv8*)(As + off);
      }
#pragma unroll
      for (int j = 0; j < 4; j++) {
        int row = wn * 64 + j * 16 + q4;
        int off = (row * 128 + kk * 64 + g * 16) ^ ((row & 7) << 4);
        bf[j] = *(const bfv8*)(Bs + off);
      }
#pragma unroll
      for (int i = 0; i < 4; i++)
#pragma unroll
        for (int j = 0; j < 4; j++)
          acc[i][j] = mfma16(af[i], bf[j], acc[i][j]);
    }
    __syncthreads();
  }

  const float scale = (mode == 0) ? QSCALE : 1.0f;
#pragma unroll
  for (int j = 0; j < 4; j++) {
    int n = n0 + wn * 64 + j * 16 + q4;
    float bv = bias[n];
#pragma unroll
    for (int i = 0; i < 4; i++) {
      int mb = m0 + wm * 64 + i * 16 + g * 4;
      if (mode == 2) {
        int bh = (mb >> 11) * 16 + (n >> 6);
        size_t base = ((size_t)bh * 64 + (n & 63)) * 2048 + (mb & 2047);
        short4v pk;
#pragma unroll
        for (int r = 0; r < 4; r++) pk[r] = f2bf(acc[i][j][r] + bv);
        *(short4v*)(o2 + base) = pk;
      } else if (mode == 3) {
#pragma unroll
        for (int r = 0; r < 4; r++)
          o3[(size_t)(mb + r) * 1024 + n] = acc[i][j][r] + bv;
      } else {
        short* O = mode == 0 ? o0 : o1;
        int bh = (mb >> 11) * 16 + (n >> 6);
#pragma unroll
        for (int r = 0; r < 4; r++)
          O[((size_t)bh * 2048 + ((mb + r) & 2047)) * 64 + (n & 63)] =
              f2bf((acc[i][j][r] + bv) * scale);
      }
    }
  }
}

// ---------------------------------------------------------------------------
// Kernel D: flash attention, 32x32 MFMA, in-register softmax+P (T12).
// grid = (16, 64) remapped XCD-aware. 4 waves/block, 32 q-rows/wave (QBLK=128).
// Swapped QK^T at 32x32: D[kv][q], col=lane&31=q, row=(reg&3)+8*(reg>>2)+4*hi.
// P redistribution for PV B-operand: cvt_pk_bf16 pairs + v_permlane32_swap
// (distinct-value operands only — identical-value scalar exchanges would get
// register-coalesced into v_permlane32_swap v5,v5; those use __shfl_xor).
// K/V staged in LDS dbuf (2x16KB), counted vmcnt(4).
__global__ __launch_bounds__(256) void attn_fwd(
    const short* __restrict__ qg, const short* __restrict__ kg,
    const short* __restrict__ vtg, short* __restrict__ og) {
  const int tid = threadIdx.x, w = tid >> 6, l = tid & 63;
  const int q5 = l & 31, hi = l >> 5;
  // XCD-aware remap: HW linear wgid W round-robins W%8 across XCDs; give each
  // XCD a contiguous bh-range so its K/V working set (~4MB) fits its L2.
  const int W = blockIdx.y * 16 + blockIdx.x;
  const int xcd = W & 7, i5 = W >> 3;
  const int bh = (xcd << 3) | (i5 & 7);
  const int qt = i5 >> 3;
  const int b = bh >> 4, h = bh & 15;
  const short* qh  = qg  + (size_t)bh * 131072;
  const short* kh  = kg  + (size_t)bh * 131072;
  const short* vth = vtg + (size_t)bh * 131072;
  const int q0 = qt * 128 + w * 32;

  __shared__ __align__(16) unsigned char smem[32768];  // K/V dbuf only

  // Q fragments (B-operand): B[k = kc*16 + hi*8 + j][col = q5]
  bfv8 qf[4];
#pragma unroll
  for (int kc = 0; kc < 4; kc++)
    qf[kc] = *(const bfv8*)(qh + (size_t)(q0 + q5) * 64 + kc * 16 + hi * 8);
  asm volatile("" ::: "memory");
  __syncthreads();   // drains vmcnt -> clean counter state

  // staging chunk geometry (per wave: 2 K chunks + 2 V chunks = 4 VMEM/tile)
  int cA = w, cB = w + 4;
  int pA = cA * 1024 + l * 16, pB = cB * 1024 + l * 16;
  int fA = (pA ^ (((pA >> 7) & 7) << 4)) >> 1;   // pre-swizzled source elem
  int fB = (pB ^ (((pB >> 7) & 7) << 4)) >> 1;

  {  // prologue: stage tile 0 into buffer 0
    unsigned char* Kb = smem;
    gload16(kh + fA, Kb + cA * 1024);
    gload16(vth + (size_t)(fA >> 6) * 2048 + (fA & 63), Kb + 8192 + cA * 1024);
    gload16(kh + fB, Kb + cB * 1024);
    gload16(vth + (size_t)(fB >> 6) * 2048 + (fB & 63), Kb + 8192 + cB * 1024);
  }

  f32x16 ot0 = (f32x16)0.f, ot1 = (f32x16)0.f;  // O^T[e][q], e-blocks 0/1
  float mst = -3.0e38f, lst = 0.f;

  for (int t = 0; t < 32; ++t) {
    unsigned char* cur = smem + (t & 1) * 16384;
    if (t < 31) {
      unsigned char* nxt = smem + ((t + 1) & 1) * 16384;
      size_t toff = (size_t)(t + 1) * 4096;
      int tcol = (t + 1) * 64;
      gload16(kh + toff + fA, nxt + cA * 1024);
      gload16(vth + (size_t)(fA >> 6) * 2048 + tcol + (fA & 63), nxt + 8192 + cA * 1024);
      gload16(kh + toff + fB, nxt + cB * 1024);
      gload16(vth + (size_t)(fB >> 6) * 2048 + tcol + (fB & 63), nxt + 8192 + cB * 1024);
      asm volatile("s_waitcnt vmcnt(4)" ::: "memory");  // cur done, nxt in flight
    } else {
      asm volatile("s_waitcnt vmcnt(0)" ::: "memory");
    }
    __builtin_amdgcn_s_barrier();

    // QK^T: st[kb] = K[kv-block kb] x Q -> D[kv][q], exp2 domain
    f32x16 st0 = (f32x16)0.f, st1 = (f32x16)0.f;
    __builtin_amdgcn_s_setprio(1);
#pragma unroll
    for (int kc = 0; kc < 4; kc++) {
      int col = kc * 32 + hi * 16;
      int r0 = q5, r1 = 32 + q5;
      bfv8 k0 = *(const bfv8*)(cur + ((r0 * 128 + col) ^ ((r0 & 7) << 4)));
      bfv8 k1 = *(const bfv8*)(cur + ((r1 * 128 + col) ^ ((r1 & 7) << 4)));
      st0 = mfma32(k0, qf[kc], st0);
      st1 = mfma32(k1, qf[kc], st1);
    }
    __builtin_amdgcn_s_setprio(0);

    // tile max over this lane's 32 kv (tree), then lane^32 exchange (shfl —
    // NOT permlane: identical-value operand pair risks register coalescing)
    f32x4 m4;
#pragma unroll
    for (int r = 0; r < 4; r++)
      m4[r] = fmaxf(fmaxf(st0[r], st0[r + 4]), fmaxf(st0[r + 8], st0[r + 12]));
#pragma unroll
    for (int r = 0; r < 4; r++)
      m4[r] = fmaxf(m4[r], fmaxf(fmaxf(st1[r], st1[r + 4]), fmaxf(st1[r + 8], st1[r + 12])));
    float mt = fmaxf(fmaxf(m4[0], m4[1]), fmaxf(m4[2], m4[3]));
    mt = fmaxf(mt, __shfl_xor(mt, 32));

    // T13 defer-rescale (exp2 domain, THR=8)
    if (__any(mt > mst + 8.0f)) {
      float mnew = fmaxf(mst, mt);
      float alpha = EXP2(mst - mnew);
      mst = mnew;
      lst *= alpha;
#pragma unroll
      for (int r = 0; r < 16; r++) { ot0[r] *= alpha; ot1[r] *= alpha; }
    }
    const float m = mst;

    // exp2 in place
#pragma unroll
    for (int r = 0; r < 16; r++) { st0[r] = EXP2(st0[r] - m); st1[r] = EXP2(st1[r] - m); }

    // row-sum (tree) + lane^32 exchange (shfl; see note above)
    f32x4 s4;
#pragma unroll
    for (int r = 0; r < 4; r++)
      s4[r] = (st0[r] + st0[r + 4]) + (st0[r + 8] + st0[r + 12]) +
              (st1[r] + st1[r + 4]) + (st1[r + 8] + st1[r + 12]);
    float ps = (s4[0] + s4[1]) + (s4[2] + s4[3]);
    ps += __shfl_xor(ps, 32);
    lst += ps;

    // pack P to bf16 and redistribute via permlane32_swap:
    // chunk c covers kv = c*16 + hi*8 + j; own regs give the 4-runs at +4*hi,
    // partner (lane^32) supplies the other 4-runs. Operands distinct -> safe.
    bfv8 pf[4];
#pragma unroll
    for (int c = 0; c < 4; c++) {
      const f32x16& s = (c < 2) ? st0 : st1;
      int rb = (c & 1) * 8;
      u32 a0 = cvtpk(s[rb + 0], s[rb + 1]), a1 = cvtpk(s[rb + 2], s[rb + 3]);
      u32 b0 = cvtpk(s[rb + 4], s[rb + 5]), b1 = cvtpk(s[rb + 6], s[rb + 7]);
      asm volatile("v_permlane32_swap_b32 %0, %1" : "+v"(a0), "+v"(b0));
      asm volatile("v_permlane32_swap_b32 %0, %1" : "+v"(a1), "+v"(b1));
      u32x4 tmp = {a0, a1, b0, b1};
      pf[c] = __builtin_bit_cast(bfv8, tmp);
    }

    // PV: ot[eb] += V^T[e-block eb] x P -> D[e][q]
    __builtin_amdgcn_s_setprio(1);
#pragma unroll
    for (int c = 0; c < 4; c++) {
      int col = c * 32 + hi * 16;
      int r0 = q5, r1 = 32 + q5;
      bfv8 v0 = *(const bfv8*)(cur + 8192 + ((r0 * 128 + col) ^ ((r0 & 7) << 4)));
      bfv8 v1 = *(const bfv8*)(cur + 8192 + ((r1 * 128 + col) ^ ((r1 & 7) << 4)));
      ot0 = mfma32(v0, pf[c], ot0);
      ot1 = mfma32(v1, pf[c], ot1);
    }
    __builtin_amdgcn_s_setprio(0);

    asm volatile("s_waitcnt lgkmcnt(0)" ::: "memory");
    __builtin_amdgcn_s_barrier();
  }

  // epilogue: aws[b, q, h*64 + e]; e = 8*k + 4*hi + j (+32 for ot1), q = q0+q5
  float inv = 1.0f / lst;
  size_t rb = ((size_t)b * 2048 + q0 + q5) * 1024 + h * 64;
#pragma unroll
  for (int k = 0; k < 4; k++) {
    bfv4 p0, p1;
#pragma unroll
    for (int j = 0; j < 4; j++) {
      p0[j] = (__bf16)(ot0[k * 4 + j] * inv);
      p1[j] = (__bf16)(ot1[k * 4 + j] * inv);
    }
    *(bfv4*)(og + rb + 8 * k + 4 * hi) = p0;
    *(bfv4*)(og + rb + 32 + 8 * k + 4 * hi) = p1;
  }
}

// ---------------------------------------------------------------------------
extern "C" void kernel_launch(void* const* d_in, const int* in_sizes, int n_in,
                              void* d_out, int out_size, void* d_ws, size_t ws_size,
                              hipStream_t stream) {
  const float* Query = (const float*)d_in[0];
  const float* Key   = (const float*)d_in[1];
  const float* Value = (const float*)d_in[2];
  const float* Wq    = (const float*)d_in[3];
  const float* bq    = (const float*)d_in[4];
  const float* Wk    = (const float*)d_in[5];
  const float* bk    = (const float*)d_in[6];
  const float* Wv    = (const float*)d_in[7];
  const float* bv    = (const float*)d_in[8];
  const float* Wo    = (const float*)d_in[9];
  const float* bo    = (const float*)d_in[10];
  float* out = (float*)d_out;

  short* ws   = (short*)d_ws;
  short* WT   = ws;                      // 4 x 1Mi bf16 = 8 MiB
  short* Xbf  = ws + 4 * 1048576;        // [3][8192][1024] bf16 = 48 MiB
  short* qws  = Xbf + 3 * 8388608;       // [B*H][S][64] = 16 MiB
  short* kws  = qws + 8388608;
  short* vtws = kws + 8388608;           // [B*H][64][S]
  short* aws  = Xbf;                     // alias: Xbf dead after proj GEMMs

  hipLaunchKernelGGL(cvt_to_bf16, dim3(8192, 1, 1), dim3(256, 1, 1), 0, stream,
                     Query, Key, Value, Xbf);
  hipLaunchKernelGGL(transpose_w, dim3(16, 16, 4), dim3(256, 1, 1), 0, stream,
                     Wq, Wk, Wv, Wo, WT);
  hipLaunchKernelGGL(gemm128, dim3(8, 64, 3), dim3(256, 1, 1), 0, stream,
                     Xbf, Xbf + 8388608, Xbf + 2 * 8388608, aws, WT,
                     bq, bk, bv, bo, qws, kws, vtws, out, 0);
  hipLaunchKernelGGL(attn_fwd, dim3(16, 64, 1), dim3(256, 1, 1), 0, stream,
                     qws, kws, vtws, aws);
  hipLaunchKernelGGL(gemm128, dim3(8, 64, 1), dim3(256, 1, 1), 0, stream,
                     Xbf, Xbf + 8388608, Xbf + 2 * 8388608, aws, WT,
                     bq, bk, bv, bo, qws, kws, vtws, out, 3);
}